// Round 1
// baseline (1284.883 us; speedup 1.0000x reference)
//
#include <hip/hip_runtime.h>

// Problem constants
#define BB 8
#define CIN 256
#define NE 64
#define HH 128
#define WW 128
#define TOPK 8
#define CC 8              // channels staged per LDS chunk

// d_out layout (float32 view), outputs concatenated flat in return order:
// weights (B,K,H,W) | indices (B,K,H,W) as float | counts (64) | new_bias (64)
#define W_OFF  0
#define I_OFF  (BB*TOPK*HH*WW)          // 1048576
#define C_OFF  (2*BB*TOPK*HH*WW)        // 2097152
#define NB_OFF (C_OFF + NE)             // 2097216

__global__ __launch_bounds__(256) void conv_topk_kernel(
    const float* __restrict__ x, const float* __restrict__ wg,
    const float* __restrict__ bias, float* __restrict__ out,
    int* __restrict__ gcount)
{
    __shared__ float sx[CC][18][19];   // x tile + halo, padded to 19 for bank spread
    __shared__ float sw[CC][9][64];    // weights transposed: [ch][tap][expert]
    __shared__ int hist[NE];

    const int tid = threadIdx.x;
    const int tx = tid & 15, ty = tid >> 4;
    const int b   = blockIdx.z;
    const int by0 = blockIdx.y << 4;
    const int bx0 = blockIdx.x << 4;
    const float* xb = x + (size_t)b * CIN * HH * WW;

    if (tid < NE) hist[tid] = 0;

    float acc[NE];
    #pragma unroll
    for (int e = 0; e < NE; ++e) acc[e] = 0.f;

    for (int c0 = 0; c0 < CIN; c0 += CC) {
        __syncthreads();   // protect previous chunk's LDS reads
        // stage x tile (with halo, zero-padded at image edges)
        for (int i = tid; i < CC*18*18; i += 256) {
            int ch  = i / 324; int rem = i - ch * 324;
            int ly  = rem / 18; int lx = rem - ly * 18;
            int gy  = by0 - 1 + ly, gx = bx0 - 1 + lx;
            float v = 0.f;
            if ((unsigned)gy < (unsigned)HH && (unsigned)gx < (unsigned)WW)
                v = xb[(size_t)(c0 + ch) * (HH*WW) + gy * WW + gx];
            sx[ch][ly][lx] = v;
        }
        // stage weights transposed so experts are contiguous (float4-readable)
        for (int i = tid; i < CC*9*64; i += 256) {
            int ch  = i / 576; int rem = i - ch * 576;
            int tap = rem >> 6; int e = rem & 63;
            sw[ch][tap][e] = wg[(size_t)e * (CIN*9) + (size_t)(c0 + ch) * 9 + tap];
        }
        __syncthreads();

        #pragma unroll 1
        for (int ch = 0; ch < CC; ++ch) {
            float xv[9];
            #pragma unroll
            for (int ky = 0; ky < 3; ++ky)
                #pragma unroll
                for (int kx = 0; kx < 3; ++kx)
                    xv[ky*3+kx] = sx[ch][ty+ky][tx+kx];
            #pragma unroll
            for (int tap = 0; tap < 9; ++tap) {
                const float xs = xv[tap];
                #pragma unroll
                for (int e0 = 0; e0 < NE; e0 += 4) {
                    const float4 w4 = *(const float4*)(&sw[ch][tap][e0]);
                    acc[e0+0] = fmaf(xs, w4.x, acc[e0+0]);
                    acc[e0+1] = fmaf(xs, w4.y, acc[e0+1]);
                    acc[e0+2] = fmaf(xs, w4.z, acc[e0+2]);
                    acc[e0+3] = fmaf(xs, w4.w, acc[e0+3]);
                }
            }
        }
    }

    // sigmoid + routing bias (bias uniform -> scalar loads)
    #pragma unroll
    for (int e = 0; e < NE; ++e)
        acc[e] = 1.f / (1.f + __expf(-acc[e])) + bias[e];

    // top-8 by biased score, descending, lowest-index wins ties (matches lax.top_k)
    float selv[TOPK]; int seli[TOPK];
    #pragma unroll
    for (int j = 0; j < TOPK; ++j) {
        float bv = -1e38f; int bidx = 0;
        #pragma unroll
        for (int e = 0; e < NE; ++e) {
            bool gt = acc[e] > bv;
            bv   = gt ? acc[e] : bv;
            bidx = gt ? e      : bidx;
        }
        selv[j] = bv - bias[bidx];   // recover UNbiased score (exact when bias==0)
        seli[j] = bidx;
        #pragma unroll
        for (int e = 0; e < NE; ++e)   // mask out the winner (compile-time indices only)
            if (e == bidx) acc[e] = -3e38f;
    }

    // softmax over the 8 selected unbiased scores (ROUTE_SCALE == 1)
    float m = selv[0];
    #pragma unroll
    for (int j = 1; j < TOPK; ++j) m = fmaxf(m, selv[j]);
    float ex[TOPK]; float s = 0.f;
    #pragma unroll
    for (int j = 0; j < TOPK; ++j) { ex[j] = __expf(selv[j] - m); s += ex[j]; }
    const float inv = 1.f / s;

    const int py = by0 + ty, px = bx0 + tx;
    #pragma unroll
    for (int j = 0; j < TOPK; ++j) {
        size_t o = ((size_t)(b * TOPK + j) * HH + py) * WW + px;
        out[W_OFF + o] = ex[j] * inv;
        out[I_OFF + o] = (float)seli[j];
        atomicAdd(&hist[seli[j]], 1);
    }
    __syncthreads();
    if (tid < NE) atomicAdd(&gcount[tid], hist[tid]);
}

__global__ void finalize_kernel(const float* __restrict__ bias,
                                const float* __restrict__ history,
                                const int* __restrict__ gcount,
                                float* __restrict__ out)
{
    const int e = threadIdx.x;   // 64 threads = 1 wave
    float c = history[e] + (float)gcount[e];
    if (__all(c > 1e8f)) c = fmodf(c, 1e8f);
    float sum = c;
    #pragma unroll
    for (int off = 32; off > 0; off >>= 1) sum += __shfl_down(sum, off);
    float mean = __shfl(sum, 0) * (1.f/64.f);
    float d = mean - c;
    float sg = (d > 0.f) ? 1.f : ((d < 0.f) ? -1.f : 0.f);
    out[C_OFF + e]  = c;
    out[NB_OFF + e] = bias[e] + 0.001f * sg;
}

extern "C" void kernel_launch(void* const* d_in, const int* in_sizes, int n_in,
                              void* d_out, int out_size, void* d_ws, size_t ws_size,
                              hipStream_t stream) {
    const float* x       = (const float*)d_in[0];
    const float* wg      = (const float*)d_in[1];
    const float* bias    = (const float*)d_in[2];
    const float* history = (const float*)d_in[3];
    float* out  = (float*)d_out;
    int* gcount = (int*)d_ws;

    // zero the count scratch every launch (ws is poisoned once, never re-poisoned)
    hipMemsetAsync(gcount, 0, NE * sizeof(int), stream);
    conv_topk_kernel<<<dim3(WW/16, HH/16, BB), 256, 0, stream>>>(x, wg, bias, out, gcount);
    finalize_kernel<<<1, 64, 0, stream>>>(bias, history, gcount, out);
}

// Round 2
// 827.966 us; speedup vs baseline: 1.5519x; 1.5519x over previous
//
#include <hip/hip_runtime.h>

// Problem constants
#define BB 8
#define CIN 256
#define NE 64
#define HH 128
#define WW 128
#define TOPK 8
#define CC 4              // channels staged per LDS chunk
#define TS 8              // pixel tile 8x8
#define HL 10             // halo extent
#define XPAD 12           // padded x-tile row stride (floats, keeps float2 aligned)

// d_out layout (float32 view): weights | indices | counts | new_bias
#define W_OFF  0
#define I_OFF  (BB*TOPK*HH*WW)
#define C_OFF  (2*BB*TOPK*HH*WW)
#define NB_OFF (C_OFF + NE)

#define WGT_ELEMS (CIN*9*NE)            // transposed weights [c][tap][e]
#define WGT_BYTES (WGT_ELEMS*4)

__global__ void transpose_w(const float* __restrict__ wg, float* __restrict__ wgt) {
    int i = blockIdx.x * 256 + threadIdx.x;          // coalesced read over e-major layout
    if (i < WGT_ELEMS) {
        int e = i / (CIN*9);
        int r = i - e * (CIN*9);                     // r = c*9 + tap
        wgt[r * NE + e] = wg[i];
    }
}

union SmemU {
    struct { float sx[CC][HL][XPAD]; float sw[CC][9][NE]; } s;   // staging (16.9 KB)
    float scores[64][65];                                        // epilogue (16.6 KB, stride 65 = conflict-free)
};

template<bool TW>
__global__ __launch_bounds__(256) void conv_topk_kernel(
    const float* __restrict__ x, const float* __restrict__ wsrc,
    const float* __restrict__ bias, float* __restrict__ out,
    int* __restrict__ gcount)
{
    __shared__ SmemU u;
    __shared__ int hist[NE];
    __shared__ float sbias[NE];

    const int tid = threadIdx.x;
    const int b   = blockIdx.z;
    const int by0 = blockIdx.y * TS;
    const int bx0 = blockIdx.x * TS;
    const int q  = tid >> 4;           // quad 0..15 -> 2x2 pixels
    const int eg = tid & 15;           // expert group 0..15 -> 4 experts
    const int qy = q >> 2, qx = q & 3;
    const float* xb = x + (size_t)b * CIN * HH * WW;

    if (tid < NE) { hist[tid] = 0; sbias[tid] = bias[tid]; }

    float acc[4][4];                   // [pixel 2x2][expert 4]
    #pragma unroll
    for (int p = 0; p < 4; ++p)
        #pragma unroll
        for (int j = 0; j < 4; ++j) acc[p][j] = 0.f;

    for (int c0 = 0; c0 < CIN; c0 += CC) {
        __syncthreads();
        // stage x tile (halo, zero-padded at edges): CC*10*10 = 400 elems
        for (int i = tid; i < CC*HL*HL; i += 256) {
            int ch = i / (HL*HL); int rem = i - ch * (HL*HL);
            int ly = rem / HL, lx = rem - ly * HL;
            int gy = by0 - 1 + ly, gx = bx0 - 1 + lx;
            float v = 0.f;
            if ((unsigned)gy < (unsigned)HH && (unsigned)gx < (unsigned)WW)
                v = xb[(size_t)(c0 + ch) * (HH*WW) + gy * WW + gx];
            u.s.sx[ch][ly][lx] = v;
        }
        // stage weights: CC*9*64 = 2304 elems
        if (TW) {
            // transposed copy in ws: contiguous, fully coalesced
            const float* src = wsrc + (size_t)c0 * (9*NE);
            float* dst = &u.s.sw[0][0][0];
            for (int i = tid; i < CC*9*NE; i += 256) dst[i] = src[i];
        } else {
            for (int i = tid; i < CC*9*NE; i += 256) {
                int ch = i / 576; int rem = i - ch * 576;
                int tap = rem >> 6; int e = rem & 63;
                u.s.sw[ch][tap][e] = wsrc[(size_t)e * (CIN*9) + (size_t)(c0 + ch) * 9 + tap];
            }
        }
        __syncthreads();

        #pragma unroll
        for (int ch = 0; ch < CC; ++ch) {
            // 4x4 input window for this quad: rows qy*2+0..3, cols qx*2+0..3 (padded coords)
            float xv[4][4];
            #pragma unroll
            for (int r = 0; r < 4; ++r) {
                const float2 a  = *(const float2*)&u.s.sx[ch][qy*2 + r][qx*2];
                const float2 bb = *(const float2*)&u.s.sx[ch][qy*2 + r][qx*2 + 2];
                xv[r][0] = a.x; xv[r][1] = a.y; xv[r][2] = bb.x; xv[r][3] = bb.y;
            }
            #pragma unroll
            for (int ky = 0; ky < 3; ++ky) {
                #pragma unroll
                for (int kx = 0; kx < 3; ++kx) {
                    const float4 w4 = *(const float4*)&u.s.sw[ch][ky*3+kx][eg*4];
                    #pragma unroll
                    for (int p = 0; p < 4; ++p) {
                        const float xs = xv[(p>>1) + ky][(p&1) + kx];
                        acc[p][0] = fmaf(xs, w4.x, acc[p][0]);
                        acc[p][1] = fmaf(xs, w4.y, acc[p][1]);
                        acc[p][2] = fmaf(xs, w4.z, acc[p][2]);
                        acc[p][3] = fmaf(xs, w4.w, acc[p][3]);
                    }
                }
            }
        }
    }

    // ---- epilogue: sigmoid + bias -> LDS scores, then per-pixel top-8 ----
    __syncthreads();   // staging buffers dead; reuse as scores
    #pragma unroll
    for (int p = 0; p < 4; ++p) {
        const int py = qy*2 + (p>>1), px = qx*2 + (p&1);
        const int pix = py * TS + px;
        #pragma unroll
        for (int j = 0; j < 4; ++j)
            u.scores[pix][eg*4 + j] = 1.f / (1.f + __expf(-acc[p][j])) + sbias[eg*4 + j];
    }
    __syncthreads();

    if (tid < 64) {
        float* row = u.scores[tid];
        float selv[TOPK]; int seli[TOPK];
        #pragma unroll
        for (int j = 0; j < TOPK; ++j) {
            float bv = -1e38f; int bidx = 0;
            #pragma unroll
            for (int e = 0; e < NE; ++e) {      // strict >, lowest index wins: matches lax.top_k
                float v = row[e];
                bool gt = v > bv;
                bv   = gt ? v : bv;
                bidx = gt ? e : bidx;
            }
            selv[j] = bv - sbias[bidx];         // recover UNbiased score
            seli[j] = bidx;
            row[bidx] = -3e38f;                 // mask winner (LDS write, dynamic index ok)
        }
        // softmax over 8 selected unbiased scores (ROUTE_SCALE == 1)
        float m = selv[0];
        #pragma unroll
        for (int j = 1; j < TOPK; ++j) m = fmaxf(m, selv[j]);
        float ex[TOPK]; float s = 0.f;
        #pragma unroll
        for (int j = 0; j < TOPK; ++j) { ex[j] = __expf(selv[j] - m); s += ex[j]; }
        const float inv = 1.f / s;

        const int py = by0 + (tid >> 3), px = bx0 + (tid & 7);
        #pragma unroll
        for (int j = 0; j < TOPK; ++j) {
            size_t o = ((size_t)(b * TOPK + j) * HH + py) * WW + px;
            out[W_OFF + o] = ex[j] * inv;
            out[I_OFF + o] = (float)seli[j];
            atomicAdd(&hist[seli[j]], 1);
        }
    }
    __syncthreads();
    if (tid < NE) atomicAdd(&gcount[tid], hist[tid]);
}

__global__ void finalize_kernel(const float* __restrict__ bias,
                                const float* __restrict__ history,
                                const int* __restrict__ gcount,
                                float* __restrict__ out)
{
    const int e = threadIdx.x;   // 64 threads = 1 wave
    float c = history[e] + (float)gcount[e];
    if (__all(c > 1e8f)) c = fmodf(c, 1e8f);
    float sum = c;
    #pragma unroll
    for (int off = 32; off > 0; off >>= 1) sum += __shfl_down(sum, off);
    float mean = __shfl(sum, 0) * (1.f/64.f);
    float d = mean - c;
    float sg = (d > 0.f) ? 1.f : ((d < 0.f) ? -1.f : 0.f);
    out[C_OFF + e]  = c;
    out[NB_OFF + e] = bias[e] + 0.001f * sg;
}

extern "C" void kernel_launch(void* const* d_in, const int* in_sizes, int n_in,
                              void* d_out, int out_size, void* d_ws, size_t ws_size,
                              hipStream_t stream) {
    const float* x       = (const float*)d_in[0];
    const float* wg      = (const float*)d_in[1];
    const float* bias    = (const float*)d_in[2];
    const float* history = (const float*)d_in[3];
    float* out = (float*)d_out;

    const dim3 grid(WW/TS, HH/TS, BB);   // 16x16x8 = 2048 blocks = 8/CU

    if (ws_size >= WGT_BYTES + NE * sizeof(int)) {
        float* wgt  = (float*)d_ws;
        int* gcount = (int*)((char*)d_ws + WGT_BYTES);
        hipMemsetAsync(gcount, 0, NE * sizeof(int), stream);
        transpose_w<<<(WGT_ELEMS + 255) / 256, 256, 0, stream>>>(wg, wgt);
        conv_topk_kernel<true><<<grid, 256, 0, stream>>>(x, wgt, bias, out, gcount);
        finalize_kernel<<<1, 64, 0, stream>>>(bias, history, gcount, out);
    } else {
        int* gcount = (int*)d_ws;
        hipMemsetAsync(gcount, 0, NE * sizeof(int), stream);
        conv_topk_kernel<false><<<grid, 256, 0, stream>>>(x, wg, bias, out, gcount);
        finalize_kernel<<<1, 64, 0, stream>>>(bias, history, gcount, out);
    }
}

// Round 3
// 162.183 us; speedup vs baseline: 7.9224x; 5.1051x over previous
//
#include <hip/hip_runtime.h>

// Problem constants
#define BB 8
#define CIN 256
#define NE 64
#define HH 128
#define WW 128
#define TOPK 8

#define TS   16               // 16x16 pixel tile per block
#define HALO 18
#define NSP  (HALO*HALO)      // 324 spatial positions incl halo
#define CC   32               // channels per K-chunk (one 16x16x32 K-step per tap)
#define NCH  (CIN/CC)         // 8 chunks
#define ROWB 144              // LDS row bytes: [32ch hi bf16 (64B) | 32ch lo (64B) | 16B pad]

// d_out layout (float32 view): weights | indices | counts | new_bias
#define W_OFF  0
#define I_OFF  (BB*TOPK*HH*WW)
#define C_OFF  (2*BB*TOPK*HH*WW)
#define NB_OFF (C_OFF + NE)

#define WROWS (NCH*9*NE)            // 4608 rows in the split-weight image
#define WSPLIT_BYTES (WROWS*ROWB)   // 663552 B

typedef __attribute__((ext_vector_type(8))) __bf16 bf16x8;   // 4 VGPR MFMA operand
typedef __attribute__((ext_vector_type(4))) float f32x4;     // 4 VGPR accumulator

// ---- prep: split weights to bf16 hi/lo in the exact LDS image layout ----
// wsplit row index: ((chunk*3 + ky)*3 + kx)*64 + e ; row = hi ch0..31 | lo ch0..31 | pad
__global__ void split_w(const float* __restrict__ wg, char* __restrict__ wsplit) {
    int i = blockIdx.x * 256 + threadIdx.x;
    if (i >= WROWS * 16) return;
    int cp  = i & 15;                 // channel pair within chunk
    int row = i >> 4;
    int c   = row / (9 * NE);
    int r2  = row % (9 * NE);
    int ky  = r2 / (3 * NE);
    int r3  = r2 % (3 * NE);
    int kx  = r3 / NE;
    int e   = r3 % NE;
    int ch  = c * CC + cp * 2;
    const float* src = wg + ((size_t)e * CIN + ch) * 9 + ky * 3 + kx;
    float f0 = src[0], f1 = src[9];
    unsigned u0 = __float_as_uint(f0), u1 = __float_as_uint(f1);
    float r0 = f0 - __uint_as_float(u0 & 0xffff0000u);
    float r1 = f1 - __uint_as_float(u1 & 0xffff0000u);
    char* base = wsplit + (size_t)row * ROWB;
    *(unsigned*)(base + cp * 4)      = (u0 >> 16) | (u1 & 0xffff0000u);
    *(unsigned*)(base + 64 + cp * 4) = (__float_as_uint(r0) >> 16) | (__float_as_uint(r1) & 0xffff0000u);
}

union Smem {
    struct { char x[NSP * ROWB]; char w[3 * NE * ROWB]; } st;  // 46656 + 27648 B
    float scores[256][65];                                     // 66560 B (epilogue)
};

__global__ __launch_bounds__(256) void conv_mfma_kernel(
    const float* __restrict__ x, const char* __restrict__ wsplit,
    const float* __restrict__ bias, float* __restrict__ out,
    int* __restrict__ gcount)
{
    __shared__ __align__(16) Smem sm;
    __shared__ int hist[NE];
    __shared__ float sbias[NE];

    const int tid  = threadIdx.x;
    const int lane = tid & 63;
    const int wv   = tid >> 6;            // wave 0..3
    const int b    = blockIdx.z;
    const int by0  = blockIdx.y * TS, bx0 = blockIdx.x * TS;
    const float* xb = x + (size_t)b * CIN * HH * WW;

    if (tid < NE) { hist[tid] = 0; sbias[tid] = bias[tid]; }

    const int er = lane & 15;             // A: pixel col / B: expert-in-tile / C: col
    const int kg = lane >> 4;             // k-group 0..3 (8 ch each)

    f32x4 acc[4][4];                      // [Mtile][Ntile]
    #pragma unroll
    for (int m = 0; m < 4; ++m)
        #pragma unroll
        for (int n = 0; n < 4; ++n) acc[m][n] = (f32x4){0.f, 0.f, 0.f, 0.f};

    for (int c = 0; c < NCH; ++c) {
        __syncthreads();                  // previous chunk's LDS reads complete
        // ---- stage x chunk: 324 spatial x 32 ch, split hi/lo ----
        for (int g = tid; g < NSP * 8; g += 256) {
            int s  = g % NSP, cq = g / NSP;          // s fast -> coalesced global reads
            int gy = by0 - 1 + s / HALO, gx = bx0 - 1 + s % HALO;
            bool ok = ((unsigned)gy < (unsigned)HH) && ((unsigned)gx < (unsigned)WW);
            const float* p = xb + (size_t)(c * CC + cq * 4) * (HH * WW) + gy * WW + gx;
            float f0 = ok ? p[0]            : 0.f;
            float f1 = ok ? p[HH * WW]      : 0.f;
            float f2 = ok ? p[2 * HH * WW]  : 0.f;
            float f3 = ok ? p[3 * HH * WW]  : 0.f;
            unsigned u0 = __float_as_uint(f0), u1 = __float_as_uint(f1);
            unsigned u2 = __float_as_uint(f2), u3 = __float_as_uint(f3);
            float r0 = f0 - __uint_as_float(u0 & 0xffff0000u);
            float r1 = f1 - __uint_as_float(u1 & 0xffff0000u);
            float r2 = f2 - __uint_as_float(u2 & 0xffff0000u);
            float r3 = f3 - __uint_as_float(u3 & 0xffff0000u);
            uint2 hi2, lo2;
            hi2.x = (u0 >> 16) | (u1 & 0xffff0000u);
            hi2.y = (u2 >> 16) | (u3 & 0xffff0000u);
            lo2.x = (__float_as_uint(r0) >> 16) | (__float_as_uint(r1) & 0xffff0000u);
            lo2.y = (__float_as_uint(r2) >> 16) | (__float_as_uint(r3) & 0xffff0000u);
            *(uint2*)(&sm.st.x[s * ROWB + cq * 8])      = hi2;
            *(uint2*)(&sm.st.x[s * ROWB + 64 + cq * 8]) = lo2;
        }
        for (int ky = 0; ky < 3; ++ky) {
            if (ky) __syncthreads();      // previous ky's w reads complete
            // ---- stage w for (chunk, ky): contiguous 27648 B, conflict-free b128 copy ----
            const uint4* wsrc = (const uint4*)(wsplit + (size_t)(c * 3 + ky) * (3 * NE * ROWB));
            uint4* wdst = (uint4*)sm.st.w;
            for (int i2 = tid; i2 < (3 * NE * ROWB) / 16; i2 += 256) wdst[i2] = wsrc[i2];
            __syncthreads();

            #pragma unroll
            for (int kx = 0; kx < 3; ++kx) {
                bf16x8 Bh[4], Bl[4];
                #pragma unroll
                for (int n = 0; n < 4; ++n) {
                    const char* wr = &sm.st.w[(size_t)(kx * NE + n * 16 + er) * ROWB + kg * 16];
                    Bh[n] = *(const bf16x8*)wr;
                    Bl[n] = *(const bf16x8*)(wr + 64);
                }
                #pragma unroll
                for (int m = 0; m < 4; ++m) {
                    int s = (wv * 4 + m + ky) * HALO + er + kx;   // halo coords
                    const char* xr = &sm.st.x[(size_t)s * ROWB + kg * 16];
                    bf16x8 Ah = *(const bf16x8*)xr;
                    bf16x8 Al = *(const bf16x8*)(xr + 64);
                    #pragma unroll
                    for (int n = 0; n < 4; ++n) {
                        acc[m][n] = __builtin_amdgcn_mfma_f32_16x16x32_bf16(Ah, Bh[n], acc[m][n], 0, 0, 0);
                        acc[m][n] = __builtin_amdgcn_mfma_f32_16x16x32_bf16(Al, Bh[n], acc[m][n], 0, 0, 0);
                        acc[m][n] = __builtin_amdgcn_mfma_f32_16x16x32_bf16(Ah, Bl[n], acc[m][n], 0, 0, 0);
                    }
                }
            }
        }
    }

    // ---- epilogue: sigmoid+bias -> LDS scores [pixel][expert] ----
    __syncthreads();                      // staging buffers dead; reuse as scores
    #pragma unroll
    for (int m = 0; m < 4; ++m) {
        int pixbase = (wv * 4 + m) * 16 + kg * 4;   // C row = (lane>>4)*4 + reg
        #pragma unroll
        for (int n = 0; n < 4; ++n) {
            int e = n * 16 + er;                    // C col = lane&15
            float bval = sbias[e];
            #pragma unroll
            for (int r = 0; r < 4; ++r)
                sm.scores[pixbase + r][e] = 1.f / (1.f + __expf(-acc[m][n][r])) + bval;
        }
    }
    __syncthreads();

    // ---- per-pixel top-8 (strict >, lowest index wins: matches lax.top_k) ----
    {
        float* row = sm.scores[tid];
        float selv[TOPK]; int seli[TOPK];
        #pragma unroll
        for (int j = 0; j < TOPK; ++j) {
            float bv = -1e38f; int bidx = 0;
            #pragma unroll
            for (int e = 0; e < NE; ++e) {
                float v = row[e];
                bool gt = v > bv;
                bv   = gt ? v : bv;
                bidx = gt ? e : bidx;
            }
            selv[j] = bv - sbias[bidx];    // recover UNbiased score
            seli[j] = bidx;
            row[bidx] = -3e38f;            // mask winner
        }
        float mx = selv[0];
        #pragma unroll
        for (int j = 1; j < TOPK; ++j) mx = fmaxf(mx, selv[j]);
        float ex[TOPK]; float ssum = 0.f;
        #pragma unroll
        for (int j = 0; j < TOPK; ++j) { ex[j] = __expf(selv[j] - mx); ssum += ex[j]; }
        const float inv = 1.f / ssum;

        const int pyg = by0 + (tid >> 4), pxg = bx0 + (tid & 15);
        #pragma unroll
        for (int j = 0; j < TOPK; ++j) {
            size_t o = ((size_t)(b * TOPK + j) * HH + pyg) * WW + pxg;
            out[W_OFF + o] = ex[j] * inv;
            out[I_OFF + o] = (float)seli[j];
            atomicAdd(&hist[seli[j]], 1);
        }
    }
    __syncthreads();
    if (tid < NE) atomicAdd(&gcount[tid], hist[tid]);
}

__global__ void finalize_kernel(const float* __restrict__ bias,
                                const float* __restrict__ history,
                                const int* __restrict__ gcount,
                                float* __restrict__ out)
{
    const int e = threadIdx.x;   // 64 threads = 1 wave
    float c = history[e] + (float)gcount[e];
    if (__all(c > 1e8f)) c = fmodf(c, 1e8f);
    float sum = c;
    #pragma unroll
    for (int off = 32; off > 0; off >>= 1) sum += __shfl_down(sum, off);
    float mean = __shfl(sum, 0) * (1.f / 64.f);
    float d = mean - c;
    float sg = (d > 0.f) ? 1.f : ((d < 0.f) ? -1.f : 0.f);
    out[C_OFF + e]  = c;
    out[NB_OFF + e] = bias[e] + 0.001f * sg;
}

extern "C" void kernel_launch(void* const* d_in, const int* in_sizes, int n_in,
                              void* d_out, int out_size, void* d_ws, size_t ws_size,
                              hipStream_t stream) {
    const float* x       = (const float*)d_in[0];
    const float* wg      = (const float*)d_in[1];
    const float* bias    = (const float*)d_in[2];
    const float* history = (const float*)d_in[3];
    float* out = (float*)d_out;

    char* wsplit = (char*)d_ws;
    int* gcount  = (int*)((char*)d_ws + WSPLIT_BYTES);

    hipMemsetAsync(gcount, 0, NE * sizeof(int), stream);
    split_w<<<(WROWS * 16 + 255) / 256, 256, 0, stream>>>(wg, wsplit);
    conv_mfma_kernel<<<dim3(WW / TS, HH / TS, BB), 256, 0, stream>>>(x, wsplit, bias, out, gcount);
    finalize_kernel<<<1, 64, 0, stream>>>(bias, history, gcount, out);
}